// Round 1
// baseline (463.749 us; speedup 1.0000x reference)
//
// Fused RippleNet forward: ONE cooperative kernel (bin -> scan/scatter -> pairs
// -> attn -> finalize) replacing memset + 4 dispatches.
// R10 theory: no prior kernel ranked in rocprof top-5 (fills @42us outrank all),
// so each was <41.6us while justified work is ~20-30us total -> the ~100us
// residual is per-dispatch launch+drain overhead. Fuse with cg grid syncs.
// 768 blocks @ __launch_bounds__(256,3): co-residency guaranteed
// (3 blk/CU, 12 waves/CU, LDS 25.6KB*3 = 77KB < 160KB).
#include <hip/hip_runtime.h>
#include <hip/hip_cooperative_groups.h>
#include <math.h>

#define N_ENTITY 200000
#define N_REL 32
#define DIM 64
#define N_HOP 2
#define N_MEM 32
#define BATCH 1024
#define PAIR_PER_HOP (BATCH * N_MEM)       // 32768
#define N_PAIR (N_HOP * PAIR_PER_HOP)      // 65536
#define CAP 3072                           // per-relation bucket capacity
#define NBLOCKS 768                        // 3 blocks/CU on 256 CUs
#define JBLK 24                            // blocks per relation (768/32)
#define WPB 4                              // waves per block
#define NBLK_PAIRS (JBLK * N_REL * WPB)    // 3072 per-wave reduction slots
#define TPAD 68                            // LDS transpose row pitch
#define BINB 64                            // binning blocks (1024 pairs each)

namespace cg = cooperative_groups;

typedef __attribute__((ext_vector_type(8))) short short8;   // 8 bf16
typedef __attribute__((ext_vector_type(4))) float floatx4;  // C/D frag

// ---------------- shared memory union (per-phase views) ----------------
struct SmemA { int hist[N_REL]; int cur[N_REL]; };
struct __align__(16) SmemB {
    float sTr[WPB][16 * TPAD];   // 17.4 KB transpose bufs
    short8 sB[512];              // 8 KB packed bf16 R^T
    float sRed[WPB];
};
struct __align__(16) SmemC {
    float sAtt[N_MEM];
    float sO[4][DIM];
    float sV[DIM];
};
struct SmemD { float sb[4], sk[4], sl[4]; };
union __align__(16) Smem { SmemA a; SmemB b; SmemC c; SmemD d; };

// ---------------- helpers ----------------
__device__ __forceinline__ float wave_reduce_sum(float v) {
    v += __shfl_xor(v, 1);
    v += __shfl_xor(v, 2);
    v += __shfl_xor(v, 4);
    v += __shfl_xor(v, 8);
    v += __shfl_xor(v, 16);
    v += __shfl_xor(v, 32);
    return v;
}

__device__ __forceinline__ unsigned short f2b(float x) {
    union { float f; unsigned u; } c; c.f = x;
    const unsigned r = (c.u + 0x7FFFu + ((c.u >> 16) & 1u)) >> 16;
    return (unsigned short)r;
}

__device__ __forceinline__ float b2f(short s) {
    union { unsigned u; float f; } c;
    c.u = ((unsigned)(unsigned short)s) << 16;
    return c.f;
}

__device__ __forceinline__ short8 pack8(const float4 a, const float4 b) {
    short8 s;
    s[0] = (short)f2b(a.x); s[1] = (short)f2b(a.y);
    s[2] = (short)f2b(a.z); s[3] = (short)f2b(a.w);
    s[4] = (short)f2b(b.x); s[5] = (short)f2b(b.y);
    s[6] = (short)f2b(b.z); s[7] = (short)f2b(b.w);
    return s;
}

__device__ __forceinline__ float sq4(const float4 a) {
    return a.x * a.x + a.y * a.y + a.z * a.z + a.w * a.w;
}

__device__ __forceinline__ float dot4(const float4 a, const float4 b) {
    return a.x * b.x + a.y * b.y + a.z * b.z + a.w * b.w;
}

// ---------------------------------------------------------------------------
// Phase A1: per-block relation histogram (64 blocks x 1024 pairs).
// No global atomics, no pre-zeroed memory needed (ws is poisoned).
// ---------------------------------------------------------------------------
__device__ __forceinline__ void phaseA1(const int bid, const int tid,
                                        const int* __restrict__ mr,
                                        int* __restrict__ g_hist, SmemA& sa) {
    const int pbase = bid * 1024;
    if (tid < N_REL) sa.hist[tid] = 0;
    __syncthreads();
    #pragma unroll
    for (int u = 0; u < 4; ++u)
        atomicAdd(&sa.hist[mr[pbase + u * 256 + tid]], 1);
    __syncthreads();
    if (tid < N_REL) g_hist[bid * N_REL + tid] = sa.hist[tid];
}

// ---------------------------------------------------------------------------
// Phase A2: exclusive scan over block hists + scatter into relation buckets.
// Last block also publishes per-relation totals (g_cnt).
// ---------------------------------------------------------------------------
__device__ __forceinline__ void phaseA2(const int bid, const int tid,
                                        const int* __restrict__ mr,
                                        const int* __restrict__ g_hist,
                                        int* __restrict__ list,
                                        int* __restrict__ g_cnt, SmemA& sa) {
    if (tid < N_REL) {
        int off = 0;
        for (int b = 0; b < bid; ++b) off += g_hist[b * N_REL + tid];
        sa.cur[tid] = off;
        if (bid == BINB - 1) g_cnt[tid] = off + g_hist[bid * N_REL + tid];
    }
    __syncthreads();
    const int pbase = bid * 1024;
    #pragma unroll
    for (int u = 0; u < 4; ++u) {
        const int idx = pbase + u * 256 + tid;
        const int r = mr[idx];
        const int pos = atomicAdd(&sa.cur[r], 1);
        if (pos < CAP) list[r * CAP + pos] = idx;
    }
}

// ---------------------------------------------------------------------------
// Phase B: MFMA gather-GEMM pairs (same structure as prior K1, JBLK=24).
// ---------------------------------------------------------------------------
__device__ __forceinline__ void phaseB(
    const int bid, const int tid,
    const int* __restrict__ items,
    const int* __restrict__ mh,
    const int* __restrict__ mt,
    const float* __restrict__ item_table,
    const float* __restrict__ rel_table,
    const int* __restrict__ g_cnt,
    const int* __restrict__ list,
    float* __restrict__ wsL,
    unsigned short* __restrict__ wsRh,
    float* __restrict__ ws_kge,
    float* __restrict__ ws_l2,
    SmemB& sb)
{
    const int lane = tid & 63;
    const int w = tid >> 6;
    const int j = bid % JBLK;
    const int r = bid / JBLK;
    const int n = min(g_cnt[r], CAP);

    const int m16 = lane & 15;
    const int quad = lane >> 4;
    const int rb = r * CAP;
    const int wave_id = j * WPB + w;

    float* buf = &sb.sTr[w][0];

    // ---- first-tile index chase, issued early (latency overlap) ----
    int tau = wave_id;
    int p = 0, hidx = 0, tidx = 0, iidx = 0;
    if (tau * 16 < n) {
        const int pos = min(tau * 16 + m16, n - 1);
        p = list[rb + pos];
        hidx = mh[p];
        tidx = mt[p];
        iidx = (p < PAIR_PER_HOP) ? items[p >> 5] : 0;
    }

    // ---- cooperative B staging: slot = s*256 + tn*64 + lane_s ----
    {
        const float* __restrict__ Rb = rel_table + (size_t)r * (DIM * DIM);
        float rsq = 0.f;
        #pragma unroll
        for (int u = 0; u < 2; ++u) {
            const int slot = tid + 256 * u;
            const int s = slot >> 8;
            const int tn = (slot >> 6) & 3;
            const int ls = slot & 63;
            const float* src = Rb + (size_t)(16 * tn + (ls & 15)) * DIM
                             + 32 * s + 8 * (ls >> 4);
            const float4 a = *(const float4*)src;
            const float4 b = *(const float4*)(src + 4);
            rsq += sq4(a) + sq4(b);
            sb.sB[slot] = pack8(a, b);
        }
        rsq = wave_reduce_sum(rsq);
        if (lane == 0) sb.sRed[w] = rsq;
    }
    __syncthreads();
    const float Rsum = sb.sRed[0] + sb.sRed[1] + sb.sRed[2] + sb.sRed[3];

    // ---- each wave's B fragments: 8 conflict-free ds_read_b128 ----
    short8 Bf[2][4];
    #pragma unroll
    for (int s = 0; s < 2; ++s)
        #pragma unroll
        for (int tn = 0; tn < 4; ++tn)
            Bf[s][tn] = sb.sB[s * 256 + tn * 64 + lane];

    float kge = 0.f;
    float l2ht = 0.f;
    int cnt = 0;

    for (; tau * 16 < n; tau += JBLK * WPB) {
        const int base = tau * 16;
        const bool mvalid = (base + m16) < n;
        const bool hop0 = p < PAIR_PER_HOP;

        // ---- A rows + hoisted v0 row, all issued together ----
        const float* __restrict__ hp = item_table + (size_t)hidx * DIM + 8 * quad;
        const float* __restrict__ tp = item_table + (size_t)tidx * DIM + 8 * quad;
        const float4 h0a = *(const float4*)hp;
        const float4 h0b = *(const float4*)(hp + 4);
        const float4 h1a = *(const float4*)(hp + 32);
        const float4 h1b = *(const float4*)(hp + 36);
        const float4 t0a = *(const float4*)tp;
        const float4 t0b = *(const float4*)(tp + 4);
        const float4 t1a = *(const float4*)(tp + 32);
        const float4 t1b = *(const float4*)(tp + 36);

        float4 va0, va1, va2, va3;
        va0 = va1 = va2 = va3 = make_float4(0.f, 0.f, 0.f, 0.f);
        if (hop0) {
            const float* __restrict__ vp =
                item_table + (size_t)iidx * DIM + 16 * quad;
            va0 = *(const float4*)vp;
            va1 = *(const float4*)(vp + 4);
            va2 = *(const float4*)(vp + 8);
            va3 = *(const float4*)(vp + 12);
        }

        // ---- prefetch next tile's indices ----
        const int tau2 = tau + JBLK * WPB;
        int p2 = 0, h2 = 0, t2 = 0, i2 = 0;
        if (tau2 * 16 < n) {
            const int pos2 = min(tau2 * 16 + m16, n - 1);
            p2 = list[rb + pos2];
            h2 = mh[p2];
            t2 = mt[p2];
            i2 = (p2 < PAIR_PER_HOP) ? items[p2 >> 5] : 0;
        }

        if (mvalid) {
            l2ht += sq4(h0a) + sq4(h0b) + sq4(h1a) + sq4(h1b)
                  + sq4(t0a) + sq4(t0b) + sq4(t1a) + sq4(t1b);
        }

        const short8 Ah0 = pack8(h0a, h0b);
        const short8 Ah1 = pack8(h1a, h1b);
        const short8 At0 = pack8(t0a, t0b);
        const short8 At1 = pack8(t1a, t1b);

        floatx4 Ch[4], Ct[4];
        const floatx4 z4 = {0.f, 0.f, 0.f, 0.f};
        #pragma unroll
        for (int tn = 0; tn < 4; ++tn) {
            Ch[tn] = __builtin_amdgcn_mfma_f32_16x16x32_bf16(Ah0, Bf[0][tn], z4, 0, 0, 0);
            Ch[tn] = __builtin_amdgcn_mfma_f32_16x16x32_bf16(Ah1, Bf[1][tn], Ch[tn], 0, 0, 0);
            Ct[tn] = __builtin_amdgcn_mfma_f32_16x16x32_bf16(At0, Bf[0][tn], z4, 0, 0, 0);
            Ct[tn] = __builtin_amdgcn_mfma_f32_16x16x32_bf16(At1, Bf[1][tn], Ct[tn], 0, 0, 0);
        }

        // ---- Ct transpose: C layout (row=4*quad+q, col=m16+16tn) -> rows ----
        #pragma unroll
        for (int tn = 0; tn < 4; ++tn) {
            const int col = m16 + 16 * tn;
            #pragma unroll
            for (int q = 0; q < 4; ++q)
                buf[(4 * quad + q) * TPAD + col] = Ct[tn][q];
        }
        const float* rowT = buf + m16 * TPAD;
        const float4 ct0 = *(const float4*)(rowT + 8 * quad);
        const float4 ct1 = *(const float4*)(rowT + 8 * quad + 4);
        const float4 ct2 = *(const float4*)(rowT + 32 + 8 * quad);
        const float4 ct3 = *(const float4*)(rowT + 32 + 8 * quad + 4);
        float hrt = dot4(h0a, ct0) + dot4(h0b, ct1) + dot4(h1a, ct2) + dot4(h1b, ct3);
        hrt += __shfl_xor(hrt, 16);
        hrt += __shfl_xor(hrt, 32);

        // ---- Ch transpose (same buffer; DS in-order per wave) ----
        #pragma unroll
        for (int tn = 0; tn < 4; ++tn) {
            const int col = m16 + 16 * tn;
            #pragma unroll
            for (int q = 0; q < 4; ++q)
                buf[(4 * quad + q) * TPAD + col] = Ch[tn][q];
        }
        const float* rowC = buf + m16 * TPAD;
        const float4 c0 = *(const float4*)(rowC + 16 * quad);
        const float4 c1 = *(const float4*)(rowC + 16 * quad + 4);
        const float4 c2 = *(const float4*)(rowC + 16 * quad + 8);
        const float4 c3 = *(const float4*)(rowC + 16 * quad + 12);

        // ---- hop0 logit: prefetched v0 regs . Ch ----
        float lg = dot4(va0, c0) + dot4(va1, c1) + dot4(va2, c2) + dot4(va3, c3);
        lg += __shfl_xor(lg, 16);
        lg += __shfl_xor(lg, 32);

        if (quad == 0 && mvalid) {
            kge += 1.f / (1.f + expf(-hrt));
            if (hop0) wsL[p] = lg;
        }

        // ---- hop1 Rh store: bf16, 2 x 16B ----
        if (mvalid && !hop0) {
            unsigned short* __restrict__ dst =
                wsRh + (size_t)(p - PAIR_PER_HOP) * DIM + 16 * quad;
            *(short8*)dst = pack8(c0, c1);
            *(short8*)(dst + 8) = pack8(c2, c3);
        }

        cnt += min(16, n - base);
        p = p2; hidx = h2; tidx = t2; iidx = i2;
    }

    const float l2tot = wave_reduce_sum(l2ht) + (float)cnt * Rsum;
    const float kgetot = wave_reduce_sum(kge);
    if (lane == 0) {
        const int slot = (r * JBLK + j) * WPB + w;
        ws_kge[slot] = kgetot;
        ws_l2[slot] = l2tot;
    }
}

// ---------------------------------------------------------------------------
// Phase C: per-batch attention chain (same structure as prior K2).
// All waves loop; wave 0 does the epilogue (no early return — fused kernel).
// Cross-iteration LDS hazards are ordered by the per-iteration barriers:
// waves 1-3 cannot pass barrier1 of iter i+1 until wave 0 has finished the
// iter-i epilogue (its sO reads precede its barrier1 arrival).
// ---------------------------------------------------------------------------
__device__ __forceinline__ void phaseC_one(
    const int b, const int tid,
    const int* __restrict__ items,
    const float* __restrict__ labels,
    const int* __restrict__ mt,
    const float* __restrict__ item_table,
    const float* __restrict__ W,
    const float* __restrict__ wsL,
    const unsigned short* __restrict__ wsRh,
    float* __restrict__ out,
    float* __restrict__ ws_bce,
    SmemC& sc)
{
    const int lane = tid & 63;
    const int w = tid >> 6;

    // ================= upfront prefetch (no dependences) =================
    const float v0 = item_table[(size_t)items[b] * DIM + lane];

    float l0 = 0.f;
    if (tid < N_MEM) l0 = wsL[b * N_MEM + tid];

    float treg[2][8];
    #pragma unroll
    for (int hop = 0; hop < 2; ++hop)
        #pragma unroll
        for (int q = 0; q < 8; ++q) {
            const int tidx = mt[hop * PAIR_PER_HOP + b * N_MEM + w * 8 + q];
            treg[hop][q] = item_table[(size_t)tidx * DIM + lane];
        }

    const int m1 = tid >> 3;
    const int d1 = (tid & 7) * 8;
    const short8 rv8 =
        *(const short8*)(wsRh + (size_t)(b * N_MEM + m1) * DIM + d1);

    const float lab = labels[b];

    // ================= hop 0 =================
    if (tid < N_MEM) sc.sAtt[tid] = l0;
    __syncthreads();                                   // barrier 1

    float mx = -1e30f;
    #pragma unroll
    for (int m = 0; m < N_MEM; ++m) mx = fmaxf(mx, sc.sAtt[m]);
    float se = 0.f;
    float e_loc[8];
    #pragma unroll
    for (int m = 0; m < N_MEM; ++m) {
        const float e = expf(sc.sAtt[m] - mx);
        se += e;
        if ((m >> 3) == w) e_loc[m & 7] = e;
    }
    float inv = 1.f / se;

    float op = 0.f;
    #pragma unroll
    for (int q = 0; q < 8; ++q) op = fmaf(treg[0][q], e_loc[q] * inv, op);
    sc.sO[w][lane] = op;
    __syncthreads();                                   // barrier 2

    float y0 = 0.f, v1 = 0.f;
    if (w == 0) {
        const float o0 = sc.sO[0][lane] + sc.sO[1][lane] + sc.sO[2][lane] + sc.sO[3][lane];
        y0 = o0;
        sc.sV[lane] = v0 + o0;            // stage u (wave-coherent for wave 0)
        const float4* __restrict__ Wrow = (const float4*)(W + (size_t)lane * DIM);
        float a0 = 0.f, a1 = 0.f, a2 = 0.f, a3 = 0.f;
        #pragma unroll
        for (int k = 0; k < 16; ++k) {
            const float4 w4 = Wrow[k];
            const float4 u4 = *(const float4*)&sc.sV[k * 4];
            a0 = fmaf(w4.x, u4.x, a0);
            a1 = fmaf(w4.y, u4.y, a1);
            a2 = fmaf(w4.z, u4.z, a2);
            a3 = fmaf(w4.w, u4.w, a3);
        }
        v1 = (a0 + a1) + (a2 + a3);
        sc.sV[lane] = v1;                 // publish v1 (in-order DS per wave)
    }
    __syncthreads();                                   // barrier 3

    // ================= hop 1 =================
    {
        float dp = 0.f;
        #pragma unroll
        for (int e = 0; e < 8; ++e) dp = fmaf(b2f(rv8[e]), sc.sV[d1 + e], dp);
        dp += __shfl_xor(dp, 1);
        dp += __shfl_xor(dp, 2);
        dp += __shfl_xor(dp, 4);
        if ((tid & 7) == 0) sc.sAtt[m1] = dp;
    }
    __syncthreads();                                   // barrier 4

    mx = -1e30f;
    #pragma unroll
    for (int m = 0; m < N_MEM; ++m) mx = fmaxf(mx, sc.sAtt[m]);
    se = 0.f;
    #pragma unroll
    for (int m = 0; m < N_MEM; ++m) {
        const float e = expf(sc.sAtt[m] - mx);
        se += e;
        if ((m >> 3) == w) e_loc[m & 7] = e;
    }
    inv = 1.f / se;

    op = 0.f;
    #pragma unroll
    for (int q = 0; q < 8; ++q) op = fmaf(treg[1][q], e_loc[q] * inv, op);
    sc.sO[w][lane] = op;
    __syncthreads();                                   // barrier 5

    // ================= wave-0 epilogue =================
    if (w == 0) {
        const float o1 = sc.sO[0][lane] + sc.sO[1][lane] + sc.sO[2][lane] + sc.sO[3][lane];
        const float y = y0 + o1;
        sc.sV[lane] = v1 + o1;            // u1 (wave-coherent)
        const float4* __restrict__ Wrow = (const float4*)(W + (size_t)lane * DIM);
        float a0 = 0.f, a1 = 0.f, a2 = 0.f, a3 = 0.f;
        #pragma unroll
        for (int k = 0; k < 16; ++k) {
            const float4 w4 = Wrow[k];
            const float4 u4 = *(const float4*)&sc.sV[k * 4];
            a0 = fmaf(w4.x, u4.x, a0);
            a1 = fmaf(w4.y, u4.y, a1);
            a2 = fmaf(w4.z, u4.z, a2);
            a3 = fmaf(w4.w, u4.w, a3);
        }
        const float v2 = (a0 + a1) + (a2 + a3);

        float s = wave_reduce_sum(v2 * y);
        s = 1.f / (1.f + expf(-s));
        if (lane == 0) {
            out[b] = s;
            const float logp = fmaxf(logf(s), -100.f);
            const float lognp = fmaxf(logf(1.f - s), -100.f);
            ws_bce[b] = lab * logp + (1.f - lab) * lognp;
        }
    }
}

__device__ __forceinline__ void phaseC_all(
    const int bid, const int tid,
    const int* __restrict__ items, const float* __restrict__ labels,
    const int* __restrict__ mt, const float* __restrict__ item_table,
    const float* __restrict__ W, const float* __restrict__ wsL,
    const unsigned short* __restrict__ wsRh,
    float* __restrict__ out, float* __restrict__ ws_bce, SmemC& sc)
{
    for (int b = bid; b < BATCH; b += NBLOCKS)
        phaseC_one(b, tid, items, labels, mt, item_table, W, wsL, wsRh,
                   out, ws_bce, sc);
}

// ---------------------------------------------------------------------------
// Phase D: loss finalize (block 0 only in the fused kernel).
// ---------------------------------------------------------------------------
__device__ __forceinline__ void phaseD(
    const int tid,
    const float* __restrict__ ws_bce,
    const float* __restrict__ ws_kge,
    const float* __restrict__ ws_l2,
    float* __restrict__ out, SmemD& sd)
{
    float bsum = 0.f, ksum = 0.f, lsum = 0.f;
    for (int i = tid; i < BATCH; i += 256) bsum += ws_bce[i];
    for (int i = tid; i < NBLK_PAIRS; i += 256) {
        ksum += ws_kge[i];
        lsum += ws_l2[i];
    }
    bsum = wave_reduce_sum(bsum);
    ksum = wave_reduce_sum(ksum);
    lsum = wave_reduce_sum(lsum);
    const int w = tid >> 6;
    if ((tid & 63) == 0) { sd.sb[w] = bsum; sd.sk[w] = ksum; sd.sl[w] = lsum; }
    __syncthreads();
    if (tid == 0) {
        const float bs = sd.sb[0] + sd.sb[1] + sd.sb[2] + sd.sb[3];
        const float ks = sd.sk[0] + sd.sk[1] + sd.sk[2] + sd.sk[3];
        const float ls = sd.sl[0] + sd.sl[1] + sd.sl[2] + sd.sl[3];
        const float base_loss = -bs / (float)BATCH;
        const float kge_loss = -0.01f * (ks / (float)(BATCH * N_MEM));
        const float l2_loss = 1e-7f * ls;
        out[BATCH + 0] = base_loss + kge_loss + l2_loss;
        out[BATCH + 1] = base_loss;
        out[BATCH + 2] = kge_loss;
        out[BATCH + 3] = l2_loss;
    }
}

// ---------------------------------------------------------------------------
// Fused cooperative kernel.
// ---------------------------------------------------------------------------
__global__ __launch_bounds__(256, 3) void ripple_fused(
    const int* __restrict__ items, const float* __restrict__ labels,
    const int* __restrict__ mh, const int* __restrict__ mr,
    const int* __restrict__ mt,
    const float* __restrict__ item_table, const float* __restrict__ rel_table,
    const float* __restrict__ W,
    float* __restrict__ wsL, unsigned short* __restrict__ wsRh,
    int* __restrict__ list, int* __restrict__ g_hist, int* __restrict__ g_cnt,
    float* __restrict__ ws_bce, float* __restrict__ ws_kge,
    float* __restrict__ ws_l2, float* __restrict__ out)
{
    __shared__ Smem sm;
    const int bid = (int)blockIdx.x;
    const int tid = (int)threadIdx.x;
    cg::grid_group grid = cg::this_grid();

    if (bid < BINB) phaseA1(bid, tid, mr, g_hist, sm.a);
    grid.sync();
    if (bid < BINB) phaseA2(bid, tid, mr, g_hist, list, g_cnt, sm.a);
    grid.sync();
    phaseB(bid, tid, items, mh, mt, item_table, rel_table, g_cnt, list,
           wsL, wsRh, ws_kge, ws_l2, sm.b);
    grid.sync();
    phaseC_all(bid, tid, items, labels, mt, item_table, W, wsL, wsRh,
               out, ws_bce, sm.c);
    grid.sync();
    if (bid == 0) phaseD(tid, ws_bce, ws_kge, ws_l2, out, sm.d);
}

// ---------------------------------------------------------------------------
// Fallback kernels (used only if cooperative launch is rejected).
// ---------------------------------------------------------------------------
__global__ __launch_bounds__(256) void k_bin1(
    const int* __restrict__ mr, int* __restrict__ g_hist) {
    __shared__ Smem sm;
    phaseA1((int)blockIdx.x, (int)threadIdx.x, mr, g_hist, sm.a);
}

__global__ __launch_bounds__(256) void k_bin2(
    const int* __restrict__ mr, const int* __restrict__ g_hist,
    int* __restrict__ list, int* __restrict__ g_cnt) {
    __shared__ Smem sm;
    phaseA2((int)blockIdx.x, (int)threadIdx.x, mr, g_hist, list, g_cnt, sm.a);
}

__global__ __launch_bounds__(256) void k_pairs(
    const int* __restrict__ items, const int* __restrict__ mh,
    const int* __restrict__ mt, const float* __restrict__ item_table,
    const float* __restrict__ rel_table, const int* __restrict__ g_cnt,
    const int* __restrict__ list, float* __restrict__ wsL,
    unsigned short* __restrict__ wsRh, float* __restrict__ ws_kge,
    float* __restrict__ ws_l2) {
    __shared__ Smem sm;
    phaseB((int)blockIdx.x, (int)threadIdx.x, items, mh, mt, item_table,
           rel_table, g_cnt, list, wsL, wsRh, ws_kge, ws_l2, sm.b);
}

__global__ __launch_bounds__(256) void k_attn(
    const int* __restrict__ items, const float* __restrict__ labels,
    const int* __restrict__ mt, const float* __restrict__ item_table,
    const float* __restrict__ W, const float* __restrict__ wsL,
    const unsigned short* __restrict__ wsRh, float* __restrict__ out,
    float* __restrict__ ws_bce) {
    __shared__ Smem sm;
    phaseC_all((int)blockIdx.x, (int)threadIdx.x, items, labels, mt,
               item_table, W, wsL, wsRh, out, ws_bce, sm.c);
}

__global__ __launch_bounds__(256) void k_fin(
    const float* __restrict__ ws_bce, const float* __restrict__ ws_kge,
    const float* __restrict__ ws_l2, float* __restrict__ out) {
    __shared__ Smem sm;
    phaseD((int)threadIdx.x, ws_bce, ws_kge, ws_l2, out, sm.d);
}

extern "C" void kernel_launch(void* const* d_in, const int* in_sizes, int n_in,
                              void* d_out, int out_size, void* d_ws, size_t ws_size,
                              hipStream_t stream) {
    const int* items        = (const int*)d_in[0];
    const float* labels     = (const float*)d_in[1];
    const int* mh           = (const int*)d_in[2];
    const int* mr           = (const int*)d_in[3];
    const int* mt           = (const int*)d_in[4];
    const float* item_table = (const float*)d_in[5];
    const float* rel_table  = (const float*)d_in[6];
    const float* W          = (const float*)d_in[7];
    float* out = (float*)d_out;

    // workspace: wsL[32768] f32 | wsRh[32768*64] bf16 (4.2MB) |
    //            list[N_REL*CAP] | g_hist[64*32] | g_cnt[32] |
    //            ws_bce[BATCH] | ws_kge[3072] | ws_l2[3072]
    float* ws = (float*)d_ws;
    float* wsL            = ws;
    unsigned short* wsRh  = (unsigned short*)(wsL + PAIR_PER_HOP);
    int*   list           = (int*)(wsRh + (size_t)PAIR_PER_HOP * DIM);
    int*   g_hist         = list + N_REL * CAP;
    int*   g_cnt          = g_hist + BINB * N_REL;
    float* ws_bce         = (float*)(g_cnt + N_REL);
    float* ws_kge         = ws_bce + BATCH;
    float* ws_l2          = ws_kge + NBLK_PAIRS;

    void* args[] = {
        (void*)&items, (void*)&labels, (void*)&mh, (void*)&mr, (void*)&mt,
        (void*)&item_table, (void*)&rel_table, (void*)&W,
        (void*)&wsL, (void*)&wsRh, (void*)&list, (void*)&g_hist, (void*)&g_cnt,
        (void*)&ws_bce, (void*)&ws_kge, (void*)&ws_l2, (void*)&out };

    hipError_t err = hipLaunchCooperativeKernel(
        (const void*)ripple_fused, dim3(NBLOCKS), dim3(256), args, 0, stream);
    if (err != hipSuccess) {
        (void)hipGetLastError();   // clear sticky error, take multi-kernel path
        k_bin1<<<BINB, 256, 0, stream>>>(mr, g_hist);
        k_bin2<<<BINB, 256, 0, stream>>>(mr, g_hist, list, g_cnt);
        k_pairs<<<NBLOCKS, 256, 0, stream>>>(items, mh, mt, item_table,
                                             rel_table, g_cnt, list, wsL, wsRh,
                                             ws_kge, ws_l2);
        k_attn<<<NBLOCKS, 256, 0, stream>>>(items, labels, mt, item_table, W,
                                            wsL, wsRh, out, ws_bce);
        k_fin<<<1, 256, 0, stream>>>(ws_bce, ws_kge, ws_l2, out);
    }
}

// Round 2
// 174.231 us; speedup vs baseline: 2.6617x; 2.6617x over previous
//
// RippleNet forward — multi-kernel (proven structure), R11:
//  - R10 post-mortem: cooperative grid.sync costs ~75us/sync on gfx950
//    (3072 waves polling one device-scope line) -> fusion abandoned.
//  - finalize folded into attn via last-block done-counter (saves 1 dispatch)
//  - pairs: speculative first-tile chase (list/mh/mt issue before g_cnt lands)
#include <hip/hip_runtime.h>
#include <math.h>

#define N_ENTITY 200000
#define N_REL 32
#define DIM 64
#define N_HOP 2
#define N_MEM 32
#define BATCH 1024
#define PAIR_PER_HOP (BATCH * N_MEM)       // 32768
#define N_PAIR (N_HOP * PAIR_PER_HOP)      // 65536
#define CAP 3072                           // per-relation bucket capacity (mean 2048)
#define JBLK 32                            // blocks per relation in pairs kernel
#define WPB 4                              // waves per block
#define NBLK_PAIRS (JBLK * N_REL * WPB)    // 4096 per-wave reduction slots
#define TPAD 68                            // LDS transpose row pitch

typedef __attribute__((ext_vector_type(8))) short short8;   // 8 bf16 (A/B frag)
typedef __attribute__((ext_vector_type(4))) float floatx4;  // C/D frag

__device__ __forceinline__ float wave_reduce_sum(float v) {
    v += __shfl_xor(v, 1);
    v += __shfl_xor(v, 2);
    v += __shfl_xor(v, 4);
    v += __shfl_xor(v, 8);
    v += __shfl_xor(v, 16);
    v += __shfl_xor(v, 32);
    return v;
}

__device__ __forceinline__ unsigned short f2b(float x) {
    union { float f; unsigned u; } c; c.f = x;
    const unsigned r = (c.u + 0x7FFFu + ((c.u >> 16) & 1u)) >> 16;
    return (unsigned short)r;
}

__device__ __forceinline__ float b2f(short s) {
    union { unsigned u; float f; } c;
    c.u = ((unsigned)(unsigned short)s) << 16;
    return c.f;
}

__device__ __forceinline__ short8 pack8(const float4 a, const float4 b) {
    short8 s;
    s[0] = (short)f2b(a.x); s[1] = (short)f2b(a.y);
    s[2] = (short)f2b(a.z); s[3] = (short)f2b(a.w);
    s[4] = (short)f2b(b.x); s[5] = (short)f2b(b.y);
    s[6] = (short)f2b(b.z); s[7] = (short)f2b(b.w);
    return s;
}

__device__ __forceinline__ float sq4(const float4 a) {
    return a.x * a.x + a.y * a.y + a.z * a.z + a.w * a.w;
}

__device__ __forceinline__ float dot4(const float4 a, const float4 b) {
    return a.x * b.x + a.y * b.y + a.z * b.z + a.w * b.w;
}

// ---------------------------------------------------------------------------
// K0: bucket pair indices by relation (g_cnt + g_done zeroed by memset first).
// ---------------------------------------------------------------------------
__global__ __launch_bounds__(256) void ripple_bin(
    const int* __restrict__ mr,
    int* __restrict__ g_cnt,     // [N_REL]
    int* __restrict__ list)      // [N_REL][CAP]
{
    __shared__ int hist[N_REL];
    __shared__ int cur[N_REL];
    const int tid = (int)threadIdx.x;
    const int pbase = (int)blockIdx.x * 1024;

    if (tid < N_REL) hist[tid] = 0;
    __syncthreads();

    int rv[4];
    #pragma unroll
    for (int u = 0; u < 4; ++u) {
        rv[u] = mr[pbase + u * 256 + tid];
        atomicAdd(&hist[rv[u]], 1);
    }
    __syncthreads();
    if (tid < N_REL) cur[tid] = atomicAdd(&g_cnt[tid], hist[tid]);
    __syncthreads();
    #pragma unroll
    for (int u = 0; u < 4; ++u) {
        const int r = rv[u];
        const int pos = atomicAdd(&cur[r], 1);
        if (pos < CAP) list[r * CAP + pos] = pbase + u * 256 + tid;
    }
}

// ---------------------------------------------------------------------------
// K1: MFMA gather-GEMM pairs kernel.
// R11: first-tile chase is SPECULATIVE — list/mh/mt/items loads issue without
// waiting for g_cnt (index CAP-clamped, p masked in-bounds; outputs gated by
// mvalid as before). Removes one serial global-latency hop per wave.
// ---------------------------------------------------------------------------
__global__ __launch_bounds__(256) void ripple_pairs(
    const int* __restrict__ items,
    const int* __restrict__ mh,
    const int* __restrict__ mt,
    const float* __restrict__ item_table,
    const float* __restrict__ rel_table,
    const int* __restrict__ g_cnt,
    const int* __restrict__ list,
    float* __restrict__ wsL,            // [PAIR_PER_HOP] hop0 logits
    unsigned short* __restrict__ wsRh,  // [PAIR_PER_HOP][DIM] hop1 Rh (bf16)
    float* __restrict__ ws_kge,         // [NBLK_PAIRS]
    float* __restrict__ ws_l2)          // [NBLK_PAIRS]
{
    __shared__ __align__(16) float sTr[WPB][16 * TPAD];  // 17.4 KB transpose bufs
    __shared__ __align__(16) short8 sB[512];             // 8 KB packed bf16 R^T
    __shared__ float sRed[WPB];

    const int tid = (int)threadIdx.x;
    const int lane = tid & 63;
    const int w = tid >> 6;
    const int j = (int)blockIdx.x;
    const int r = (int)blockIdx.y;

    const int m16 = lane & 15;
    const int quad = lane >> 4;
    const int rb = r * CAP;
    const int wave_id = j * WPB + w;

    float* __restrict__ buf = &sTr[w][0];

    // ---- speculative first-tile index chase (no dependence on g_cnt) ----
    int tau = wave_id;
    {
        // issued immediately; n-load below overlaps this whole chain
    }
    const int pos0 = rb + min(tau * 16 + m16, CAP - 1);
    int p = list[pos0] & (N_PAIR - 1);       // mask: garbage stays in-bounds
    int hidx = mh[p];
    int tidx = mt[p];
    int iidx = (p < PAIR_PER_HOP) ? items[p >> 5] : 0;

    const int n = min(g_cnt[r], CAP);        // overlaps the chase above

    // ---- cooperative B staging: slot = s*256 + tn*64 + lane_s ----
    {
        const float* __restrict__ Rb = rel_table + (size_t)r * (DIM * DIM);
        float rsq = 0.f;
        #pragma unroll
        for (int u = 0; u < 2; ++u) {
            const int slot = tid + 256 * u;
            const int s = slot >> 8;
            const int tn = (slot >> 6) & 3;
            const int ls = slot & 63;
            const float* src = Rb + (size_t)(16 * tn + (ls & 15)) * DIM
                             + 32 * s + 8 * (ls >> 4);
            const float4 a = *(const float4*)src;
            const float4 b = *(const float4*)(src + 4);
            rsq += sq4(a) + sq4(b);
            sB[slot] = pack8(a, b);
        }
        rsq = wave_reduce_sum(rsq);
        if (lane == 0) sRed[w] = rsq;
    }
    __syncthreads();
    const float Rsum = sRed[0] + sRed[1] + sRed[2] + sRed[3];  // exact ||R||^2

    // ---- each wave's B fragments: 8 conflict-free ds_read_b128 ----
    short8 Bf[2][4];
    #pragma unroll
    for (int s = 0; s < 2; ++s)
        #pragma unroll
        for (int tn = 0; tn < 4; ++tn)
            Bf[s][tn] = sB[s * 256 + tn * 64 + lane];

    float kge = 0.f;
    float l2ht = 0.f;
    int cnt = 0;

    for (; tau * 16 < n; tau += JBLK * WPB) {
        const int base = tau * 16;
        const bool mvalid = (base + m16) < n;
        const bool hop0 = p < PAIR_PER_HOP;

        // ---- A rows + hoisted v0 row, all issued together ----
        const float* __restrict__ hp = item_table + (size_t)hidx * DIM + 8 * quad;
        const float* __restrict__ tp = item_table + (size_t)tidx * DIM + 8 * quad;
        const float4 h0a = *(const float4*)hp;
        const float4 h0b = *(const float4*)(hp + 4);
        const float4 h1a = *(const float4*)(hp + 32);
        const float4 h1b = *(const float4*)(hp + 36);
        const float4 t0a = *(const float4*)tp;
        const float4 t0b = *(const float4*)(tp + 4);
        const float4 t1a = *(const float4*)(tp + 32);
        const float4 t1b = *(const float4*)(tp + 36);

        float4 va0, va1, va2, va3;
        va0 = va1 = va2 = va3 = make_float4(0.f, 0.f, 0.f, 0.f);
        if (hop0) {
            const float* __restrict__ vp =
                item_table + (size_t)iidx * DIM + 16 * quad;
            va0 = *(const float4*)vp;
            va1 = *(const float4*)(vp + 4);
            va2 = *(const float4*)(vp + 8);
            va3 = *(const float4*)(vp + 12);
        }

        // ---- prefetch next tile's indices ----
        const int tau2 = tau + JBLK * WPB;
        int p2 = 0, h2 = 0, t2 = 0, i2 = 0;
        if (tau2 * 16 < n) {
            const int pos2 = min(tau2 * 16 + m16, n - 1);
            p2 = list[rb + pos2];
            h2 = mh[p2];
            t2 = mt[p2];
            i2 = (p2 < PAIR_PER_HOP) ? items[p2 >> 5] : 0;
        }

        if (mvalid) {
            l2ht += sq4(h0a) + sq4(h0b) + sq4(h1a) + sq4(h1b)
                  + sq4(t0a) + sq4(t0b) + sq4(t1a) + sq4(t1b);
        }

        const short8 Ah0 = pack8(h0a, h0b);
        const short8 Ah1 = pack8(h1a, h1b);
        const short8 At0 = pack8(t0a, t0b);
        const short8 At1 = pack8(t1a, t1b);

        floatx4 Ch[4], Ct[4];
        const floatx4 z4 = {0.f, 0.f, 0.f, 0.f};
        #pragma unroll
        for (int tn = 0; tn < 4; ++tn) {
            Ch[tn] = __builtin_amdgcn_mfma_f32_16x16x32_bf16(Ah0, Bf[0][tn], z4, 0, 0, 0);
            Ch[tn] = __builtin_amdgcn_mfma_f32_16x16x32_bf16(Ah1, Bf[1][tn], Ch[tn], 0, 0, 0);
            Ct[tn] = __builtin_amdgcn_mfma_f32_16x16x32_bf16(At0, Bf[0][tn], z4, 0, 0, 0);
            Ct[tn] = __builtin_amdgcn_mfma_f32_16x16x32_bf16(At1, Bf[1][tn], Ct[tn], 0, 0, 0);
        }

        // ---- Ct transpose: C layout (row=4*quad+q, col=m16+16tn) -> rows ----
        #pragma unroll
        for (int tn = 0; tn < 4; ++tn) {
            const int col = m16 + 16 * tn;
            #pragma unroll
            for (int q = 0; q < 4; ++q)
                buf[(4 * quad + q) * TPAD + col] = Ct[tn][q];
        }
        const float* rowT = buf + m16 * TPAD;
        const float4 ct0 = *(const float4*)(rowT + 8 * quad);
        const float4 ct1 = *(const float4*)(rowT + 8 * quad + 4);
        const float4 ct2 = *(const float4*)(rowT + 32 + 8 * quad);
        const float4 ct3 = *(const float4*)(rowT + 32 + 8 * quad + 4);
        float hrt = dot4(h0a, ct0) + dot4(h0b, ct1) + dot4(h1a, ct2) + dot4(h1b, ct3);
        hrt += __shfl_xor(hrt, 16);
        hrt += __shfl_xor(hrt, 32);

        // ---- Ch transpose (same buffer; DS in-order per wave) ----
        #pragma unroll
        for (int tn = 0; tn < 4; ++tn) {
            const int col = m16 + 16 * tn;
            #pragma unroll
            for (int q = 0; q < 4; ++q)
                buf[(4 * quad + q) * TPAD + col] = Ch[tn][q];
        }
        const float* rowC = buf + m16 * TPAD;
        const float4 c0 = *(const float4*)(rowC + 16 * quad);
        const float4 c1 = *(const float4*)(rowC + 16 * quad + 4);
        const float4 c2 = *(const float4*)(rowC + 16 * quad + 8);
        const float4 c3 = *(const float4*)(rowC + 16 * quad + 12);

        // ---- hop0 logit: prefetched v0 regs . Ch ----
        float lg = dot4(va0, c0) + dot4(va1, c1) + dot4(va2, c2) + dot4(va3, c3);
        lg += __shfl_xor(lg, 16);
        lg += __shfl_xor(lg, 32);

        if (quad == 0 && mvalid) {
            kge += 1.f / (1.f + expf(-hrt));
            if (hop0) wsL[p] = lg;
        }

        // ---- hop1 Rh store: bf16, 2 x 16B ----
        if (mvalid && !hop0) {
            unsigned short* __restrict__ dst =
                wsRh + (size_t)(p - PAIR_PER_HOP) * DIM + 16 * quad;
            *(short8*)dst = pack8(c0, c1);
            *(short8*)(dst + 8) = pack8(c2, c3);
        }

        cnt += min(16, n - base);
        p = p2; hidx = h2; tidx = t2; iidx = i2;
    }

    const float l2tot = wave_reduce_sum(l2ht) + (float)cnt * Rsum;
    const float kgetot = wave_reduce_sum(kge);
    if (lane == 0) {
        const int bid = (r * JBLK + j) * WPB + w;
        ws_kge[bid] = kgetot;
        ws_l2[bid] = l2tot;
    }
}

// ---------------------------------------------------------------------------
// K2: per-batch attention chain + last-block loss finalize (R11 merge).
// ---------------------------------------------------------------------------
__global__ __launch_bounds__(256) void ripple_attn_fin(
    const int* __restrict__ items,
    const float* __restrict__ labels,
    const int* __restrict__ mt,
    const float* __restrict__ item_table,
    const float* __restrict__ W,
    const float* __restrict__ wsL,
    const unsigned short* __restrict__ wsRh,
    float* __restrict__ out,
    float* __restrict__ ws_bce,
    const float* __restrict__ ws_kge,
    const float* __restrict__ ws_l2,
    int* __restrict__ g_done)
{
    __shared__ float sAtt[N_MEM];
    __shared__ __align__(16) float sO[4][DIM];
    __shared__ __align__(16) float sV[DIM];

    const int b = (int)blockIdx.x;
    const int tid = (int)threadIdx.x;
    const int lane = tid & 63;
    const int w = tid >> 6;

    // ================= upfront prefetch (no dependences) =================
    const float v0 = item_table[(size_t)items[b] * DIM + lane];

    float l0 = 0.f;
    if (tid < N_MEM) l0 = wsL[b * N_MEM + tid];

    // t rows, both hops: wave w owns slots w*8..w*8+7 (indices wave-uniform)
    float treg[2][8];
    #pragma unroll
    for (int hop = 0; hop < 2; ++hop)
        #pragma unroll
        for (int q = 0; q < 8; ++q) {
            const int tidx = mt[hop * PAIR_PER_HOP + b * N_MEM + w * 8 + q];
            treg[hop][q] = item_table[(size_t)tidx * DIM + lane];
        }

    // hop1 Rh fragment: thread handles slot m=tid>>3, dims (tid&7)*8..+8 (bf16)
    const int m1 = tid >> 3;
    const int d1 = (tid & 7) * 8;
    const short8 rv8 =
        *(const short8*)(wsRh + (size_t)(b * N_MEM + m1) * DIM + d1);

    const float lab = labels[b];

    // ================= hop 0 =================
    if (tid < N_MEM) sAtt[tid] = l0;
    __syncthreads();

    float mx = -1e30f;
    #pragma unroll
    for (int m = 0; m < N_MEM; ++m) mx = fmaxf(mx, sAtt[m]);
    float se = 0.f;
    float e_loc[8];
    #pragma unroll
    for (int m = 0; m < N_MEM; ++m) {
        const float e = expf(sAtt[m] - mx);
        se += e;
        if ((m >> 3) == w) e_loc[m & 7] = e;
    }
    float inv = 1.f / se;

    float op = 0.f;
    #pragma unroll
    for (int q = 0; q < 8; ++q) op = fmaf(treg[0][q], e_loc[q] * inv, op);
    sO[w][lane] = op;
    __syncthreads();

    float y0 = 0.f, v1 = 0.f;
    if (w == 0) {
        const float o0 = sO[0][lane] + sO[1][lane] + sO[2][lane] + sO[3][lane];
        y0 = o0;
        sV[lane] = v0 + o0;            // stage u (wave-coherent for wave 0)
        const float4* __restrict__ Wrow = (const float4*)(W + (size_t)lane * DIM);
        float a0 = 0.f, a1 = 0.f, a2 = 0.f, a3 = 0.f;
        #pragma unroll
        for (int k = 0; k < 16; ++k) {
            const float4 w4 = Wrow[k];
            const float4 u4 = *(const float4*)&sV[k * 4];
            a0 = fmaf(w4.x, u4.x, a0);
            a1 = fmaf(w4.y, u4.y, a1);
            a2 = fmaf(w4.z, u4.z, a2);
            a3 = fmaf(w4.w, u4.w, a3);
        }
        v1 = (a0 + a1) + (a2 + a3);
        sV[lane] = v1;                 // publish v1 (in-order DS per wave)
    }
    __syncthreads();

    // ================= hop 1 =================
    {
        float dp = 0.f;
        #pragma unroll
        for (int e = 0; e < 8; ++e) dp = fmaf(b2f(rv8[e]), sV[d1 + e], dp);
        dp += __shfl_xor(dp, 1);
        dp += __shfl_xor(dp, 2);
        dp += __shfl_xor(dp, 4);
        if ((tid & 7) == 0) sAtt[m1] = dp;
    }
    __syncthreads();

    mx = -1e30f;
    #pragma unroll
    for (int m = 0; m < N_MEM; ++m) mx = fmaxf(mx, sAtt[m]);
    se = 0.f;
    #pragma unroll
    for (int m = 0; m < N_MEM; ++m) {
        const float e = expf(sAtt[m] - mx);
        se += e;
        if ((m >> 3) == w) e_loc[m & 7] = e;
    }
    inv = 1.f / se;

    op = 0.f;
    #pragma unroll
    for (int q = 0; q < 8; ++q) op = fmaf(treg[1][q], e_loc[q] * inv, op);
    sO[w][lane] = op;
    __syncthreads();

    if (w != 0) return;   // waves 1-3 done (past their last barrier)

    // ================= wave-0 epilogue =================
    const float o1 = sO[0][lane] + sO[1][lane] + sO[2][lane] + sO[3][lane];
    const float y = y0 + o1;
    sV[lane] = v1 + o1;               // u1 (wave-coherent)
    const float4* __restrict__ Wrow = (const float4*)(W + (size_t)lane * DIM);
    float a0 = 0.f, a1 = 0.f, a2 = 0.f, a3 = 0.f;
    #pragma unroll
    for (int k = 0; k < 16; ++k) {
        const float4 w4 = Wrow[k];
        const float4 u4 = *(const float4*)&sV[k * 4];
        a0 = fmaf(w4.x, u4.x, a0);
        a1 = fmaf(w4.y, u4.y, a1);
        a2 = fmaf(w4.z, u4.z, a2);
        a3 = fmaf(w4.w, u4.w, a3);
    }
    const float v2 = (a0 + a1) + (a2 + a3);

    float s = wave_reduce_sum(v2 * y);
    s = 1.f / (1.f + expf(-s));
    if (lane == 0) {
        out[b] = s;
        const float logp = fmaxf(logf(s), -100.f);
        const float lognp = fmaxf(logf(1.f - s), -100.f);
        ws_bce[b] = lab * logp + (1.f - lab) * lognp;
    }

    // ---- last-block loss finalize (release: fence before atomic) ----
    __threadfence();
    int last = 0;
    if (lane == 0) last = (atomicAdd(g_done, 1) == BATCH - 1) ? 1 : 0;
    last = __shfl(last, 0);
    if (last) {
        __threadfence();   // acquire: order reads after the counter observation
        float bsum = 0.f, ksum = 0.f, lsum = 0.f;
        for (int i = lane; i < BATCH; i += 64) bsum += ws_bce[i];
        for (int i = lane; i < NBLK_PAIRS; i += 64) {
            ksum += ws_kge[i];
            lsum += ws_l2[i];
        }
        bsum = wave_reduce_sum(bsum);
        ksum = wave_reduce_sum(ksum);
        lsum = wave_reduce_sum(lsum);
        if (lane == 0) {
            const float base_loss = -bsum / (float)BATCH;
            const float kge_loss = -0.01f * (ksum / (float)(BATCH * N_MEM));
            const float l2_loss = 1e-7f * lsum;
            out[BATCH + 0] = base_loss + kge_loss + l2_loss;
            out[BATCH + 1] = base_loss;
            out[BATCH + 2] = kge_loss;
            out[BATCH + 3] = l2_loss;
        }
    }
}

extern "C" void kernel_launch(void* const* d_in, const int* in_sizes, int n_in,
                              void* d_out, int out_size, void* d_ws, size_t ws_size,
                              hipStream_t stream) {
    const int* items        = (const int*)d_in[0];
    const float* labels     = (const float*)d_in[1];
    const int* mh           = (const int*)d_in[2];
    const int* mr           = (const int*)d_in[3];
    const int* mt           = (const int*)d_in[4];
    const float* item_table = (const float*)d_in[5];
    const float* rel_table  = (const float*)d_in[6];
    const float* W          = (const float*)d_in[7];
    float* out = (float*)d_out;

    // workspace: wsL[32768] f32 | wsRh[32768*64] bf16 (4.2MB) |
    //            list[N_REL*CAP] int | g_cnt[N_REL] | g_done[1] |
    //            ws_bce[BATCH] | ws_kge[NBLK_PAIRS] | ws_l2[NBLK_PAIRS]
    float* ws = (float*)d_ws;
    float* wsL            = ws;
    unsigned short* wsRh  = (unsigned short*)(wsL + PAIR_PER_HOP);
    int*   list           = (int*)(wsRh + (size_t)PAIR_PER_HOP * DIM);
    int*   g_cnt          = list + N_REL * CAP;
    int*   g_done         = g_cnt + N_REL;
    float* ws_bce         = (float*)(g_done + 1);
    float* ws_kge         = ws_bce + BATCH;
    float* ws_l2          = ws_kge + NBLK_PAIRS;

    hipMemsetAsync(g_cnt, 0, (N_REL + 1) * sizeof(int), stream);  // g_cnt + g_done
    ripple_bin<<<N_PAIR / 1024, 256, 0, stream>>>(mr, g_cnt, list);
    dim3 gpairs(JBLK, N_REL);
    ripple_pairs<<<gpairs, 256, 0, stream>>>(items, mh, mt, item_table, rel_table,
                                             g_cnt, list, wsL, wsRh, ws_kge, ws_l2);
    ripple_attn_fin<<<BATCH, 256, 0, stream>>>(items, labels, mt, item_table, W,
                                               wsL, wsRh, out, ws_bce,
                                               ws_kge, ws_l2, g_done);
}

// Round 3
// 132.447 us; speedup vs baseline: 3.5014x; 1.3155x over previous
//
// RippleNet forward — R12:
//  - R2 post-mortem: per-block __threadfence() = L2 wb+inv per block on gfx950
//    -> 64.7us attn. Finalize de-merged (separate 1-block kernel, proven cheap).
//  - pairs reverted to R0-proven form (g_cnt-first chase).
//  - attn REWRITTEN: one wave per batch element, ZERO __syncthreads.
//    All gathers issued upfront; softmax via lane-butterfly + __shfl broadcast;
//    per-wave LDS sV[] only (same-wave DS is in-order).
#include <hip/hip_runtime.h>
#include <math.h>

#define N_ENTITY 200000
#define N_REL 32
#define DIM 64
#define N_HOP 2
#define N_MEM 32
#define BATCH 1024
#define PAIR_PER_HOP (BATCH * N_MEM)       // 32768
#define N_PAIR (N_HOP * PAIR_PER_HOP)      // 65536
#define CAP 3072                           // per-relation bucket capacity (mean 2048)
#define JBLK 32                            // blocks per relation in pairs kernel
#define WPB 4                              // waves per block
#define NBLK_PAIRS (JBLK * N_REL * WPB)    // 4096 per-wave reduction slots
#define TPAD 68                            // LDS transpose row pitch

typedef __attribute__((ext_vector_type(8))) short short8;   // 8 bf16 (A/B frag)
typedef __attribute__((ext_vector_type(4))) float floatx4;  // C/D frag

__device__ __forceinline__ float wave_reduce_sum(float v) {
    v += __shfl_xor(v, 1);
    v += __shfl_xor(v, 2);
    v += __shfl_xor(v, 4);
    v += __shfl_xor(v, 8);
    v += __shfl_xor(v, 16);
    v += __shfl_xor(v, 32);
    return v;
}

__device__ __forceinline__ unsigned short f2b(float x) {
    union { float f; unsigned u; } c; c.f = x;
    const unsigned r = (c.u + 0x7FFFu + ((c.u >> 16) & 1u)) >> 16;
    return (unsigned short)r;
}

__device__ __forceinline__ float b2f(short s) {
    union { unsigned u; float f; } c;
    c.u = ((unsigned)(unsigned short)s) << 16;
    return c.f;
}

__device__ __forceinline__ short8 pack8(const float4 a, const float4 b) {
    short8 s;
    s[0] = (short)f2b(a.x); s[1] = (short)f2b(a.y);
    s[2] = (short)f2b(a.z); s[3] = (short)f2b(a.w);
    s[4] = (short)f2b(b.x); s[5] = (short)f2b(b.y);
    s[6] = (short)f2b(b.z); s[7] = (short)f2b(b.w);
    return s;
}

__device__ __forceinline__ float sq4(const float4 a) {
    return a.x * a.x + a.y * a.y + a.z * a.z + a.w * a.w;
}

__device__ __forceinline__ float dot4(const float4 a, const float4 b) {
    return a.x * b.x + a.y * b.y + a.z * b.z + a.w * b.w;
}

// ---------------------------------------------------------------------------
// K0: bucket pair indices by relation (g_cnt zeroed by hipMemsetAsync first).
// ---------------------------------------------------------------------------
__global__ __launch_bounds__(256) void ripple_bin(
    const int* __restrict__ mr,
    int* __restrict__ g_cnt,     // [N_REL]
    int* __restrict__ list)      // [N_REL][CAP]
{
    __shared__ int hist[N_REL];
    __shared__ int cur[N_REL];
    const int tid = (int)threadIdx.x;
    const int pbase = (int)blockIdx.x * 1024;

    if (tid < N_REL) hist[tid] = 0;
    __syncthreads();

    int rv[4];
    #pragma unroll
    for (int u = 0; u < 4; ++u) {
        rv[u] = mr[pbase + u * 256 + tid];
        atomicAdd(&hist[rv[u]], 1);
    }
    __syncthreads();
    if (tid < N_REL) cur[tid] = atomicAdd(&g_cnt[tid], hist[tid]);
    __syncthreads();
    #pragma unroll
    for (int u = 0; u < 4; ++u) {
        const int r = rv[u];
        const int pos = atomicAdd(&cur[r], 1);
        if (pos < CAP) list[r * CAP + pos] = pbase + u * 256 + tid;
    }
}

// ---------------------------------------------------------------------------
// K1: MFMA gather-GEMM pairs kernel (R0-proven form).
// ---------------------------------------------------------------------------
__global__ __launch_bounds__(256) void ripple_pairs(
    const int* __restrict__ items,
    const int* __restrict__ mh,
    const int* __restrict__ mt,
    const float* __restrict__ item_table,
    const float* __restrict__ rel_table,
    const int* __restrict__ g_cnt,
    const int* __restrict__ list,
    float* __restrict__ wsL,            // [PAIR_PER_HOP] hop0 logits
    unsigned short* __restrict__ wsRh,  // [PAIR_PER_HOP][DIM] hop1 Rh (bf16)
    float* __restrict__ ws_kge,         // [NBLK_PAIRS]
    float* __restrict__ ws_l2)          // [NBLK_PAIRS]
{
    __shared__ __align__(16) float sTr[WPB][16 * TPAD];  // 17.4 KB transpose bufs
    __shared__ __align__(16) short8 sB[512];             // 8 KB packed bf16 R^T
    __shared__ float sRed[WPB];

    const int tid = (int)threadIdx.x;
    const int lane = tid & 63;
    const int w = tid >> 6;
    const int j = (int)blockIdx.x;
    const int r = (int)blockIdx.y;
    const int n = min(g_cnt[r], CAP);

    const int m16 = lane & 15;
    const int quad = lane >> 4;
    const int rb = r * CAP;
    const int wave_id = j * WPB + w;

    float* __restrict__ buf = &sTr[w][0];

    // ---- first-tile index chase, issued early (latency overlap) ----
    int tau = wave_id;
    int p = 0, hidx = 0, tidx = 0, iidx = 0;
    if (tau * 16 < n) {
        const int pos = min(tau * 16 + m16, n - 1);
        p = list[rb + pos];              // same p across the 4 quads of m16
        hidx = mh[p];
        tidx = mt[p];
        iidx = (p < PAIR_PER_HOP) ? items[p >> 5] : 0;
    }

    // ---- cooperative B staging: slot = s*256 + tn*64 + lane_s ----
    {
        const float* __restrict__ Rb = rel_table + (size_t)r * (DIM * DIM);
        float rsq = 0.f;
        #pragma unroll
        for (int u = 0; u < 2; ++u) {
            const int slot = tid + 256 * u;
            const int s = slot >> 8;
            const int tn = (slot >> 6) & 3;
            const int ls = slot & 63;
            const float* src = Rb + (size_t)(16 * tn + (ls & 15)) * DIM
                             + 32 * s + 8 * (ls >> 4);
            const float4 a = *(const float4*)src;
            const float4 b = *(const float4*)(src + 4);
            rsq += sq4(a) + sq4(b);
            sB[slot] = pack8(a, b);
        }
        rsq = wave_reduce_sum(rsq);
        if (lane == 0) sRed[w] = rsq;
    }
    __syncthreads();
    const float Rsum = sRed[0] + sRed[1] + sRed[2] + sRed[3];  // exact ||R||^2

    // ---- each wave's B fragments: 8 conflict-free ds_read_b128 ----
    short8 Bf[2][4];
    #pragma unroll
    for (int s = 0; s < 2; ++s)
        #pragma unroll
        for (int tn = 0; tn < 4; ++tn)
            Bf[s][tn] = sB[s * 256 + tn * 64 + lane];

    float kge = 0.f;
    float l2ht = 0.f;
    int cnt = 0;

    for (; tau * 16 < n; tau += JBLK * WPB) {
        const int base = tau * 16;
        const bool mvalid = (base + m16) < n;
        const bool hop0 = p < PAIR_PER_HOP;

        // ---- A rows + hoisted v0 row, all issued together ----
        const float* __restrict__ hp = item_table + (size_t)hidx * DIM + 8 * quad;
        const float* __restrict__ tp = item_table + (size_t)tidx * DIM + 8 * quad;
        const float4 h0a = *(const float4*)hp;
        const float4 h0b = *(const float4*)(hp + 4);
        const float4 h1a = *(const float4*)(hp + 32);
        const float4 h1b = *(const float4*)(hp + 36);
        const float4 t0a = *(const float4*)tp;
        const float4 t0b = *(const float4*)(tp + 4);
        const float4 t1a = *(const float4*)(tp + 32);
        const float4 t1b = *(const float4*)(tp + 36);

        float4 va0, va1, va2, va3;
        va0 = va1 = va2 = va3 = make_float4(0.f, 0.f, 0.f, 0.f);
        if (hop0) {
            const float* __restrict__ vp =
                item_table + (size_t)iidx * DIM + 16 * quad;
            va0 = *(const float4*)vp;
            va1 = *(const float4*)(vp + 4);
            va2 = *(const float4*)(vp + 8);
            va3 = *(const float4*)(vp + 12);
        }

        // ---- prefetch next tile's indices ----
        const int tau2 = tau + JBLK * WPB;
        int p2 = 0, h2 = 0, t2 = 0, i2 = 0;
        if (tau2 * 16 < n) {
            const int pos2 = min(tau2 * 16 + m16, n - 1);
            p2 = list[rb + pos2];
            h2 = mh[p2];
            t2 = mt[p2];
            i2 = (p2 < PAIR_PER_HOP) ? items[p2 >> 5] : 0;
        }

        if (mvalid) {
            l2ht += sq4(h0a) + sq4(h0b) + sq4(h1a) + sq4(h1b)
                  + sq4(t0a) + sq4(t0b) + sq4(t1a) + sq4(t1b);
        }

        const short8 Ah0 = pack8(h0a, h0b);
        const short8 Ah1 = pack8(h1a, h1b);
        const short8 At0 = pack8(t0a, t0b);
        const short8 At1 = pack8(t1a, t1b);

        floatx4 Ch[4], Ct[4];
        const floatx4 z4 = {0.f, 0.f, 0.f, 0.f};
        #pragma unroll
        for (int tn = 0; tn < 4; ++tn) {
            Ch[tn] = __builtin_amdgcn_mfma_f32_16x16x32_bf16(Ah0, Bf[0][tn], z4, 0, 0, 0);
            Ch[tn] = __builtin_amdgcn_mfma_f32_16x16x32_bf16(Ah1, Bf[1][tn], Ch[tn], 0, 0, 0);
            Ct[tn] = __builtin_amdgcn_mfma_f32_16x16x32_bf16(At0, Bf[0][tn], z4, 0, 0, 0);
            Ct[tn] = __builtin_amdgcn_mfma_f32_16x16x32_bf16(At1, Bf[1][tn], Ct[tn], 0, 0, 0);
        }

        // ---- Ct transpose: C layout (row=4*quad+q, col=m16+16tn) -> rows ----
        #pragma unroll
        for (int tn = 0; tn < 4; ++tn) {
            const int col = m16 + 16 * tn;
            #pragma unroll
            for (int q = 0; q < 4; ++q)
                buf[(4 * quad + q) * TPAD + col] = Ct[tn][q];
        }
        const float* rowT = buf + m16 * TPAD;
        const float4 ct0 = *(const float4*)(rowT + 8 * quad);
        const float4 ct1 = *(const float4*)(rowT + 8 * quad + 4);
        const float4 ct2 = *(const float4*)(rowT + 32 + 8 * quad);
        const float4 ct3 = *(const float4*)(rowT + 32 + 8 * quad + 4);
        float hrt = dot4(h0a, ct0) + dot4(h0b, ct1) + dot4(h1a, ct2) + dot4(h1b, ct3);
        hrt += __shfl_xor(hrt, 16);
        hrt += __shfl_xor(hrt, 32);

        // ---- Ch transpose (same buffer; DS in-order per wave) ----
        #pragma unroll
        for (int tn = 0; tn < 4; ++tn) {
            const int col = m16 + 16 * tn;
            #pragma unroll
            for (int q = 0; q < 4; ++q)
                buf[(4 * quad + q) * TPAD + col] = Ch[tn][q];
        }
        const float* rowC = buf + m16 * TPAD;
        const float4 c0 = *(const float4*)(rowC + 16 * quad);
        const float4 c1 = *(const float4*)(rowC + 16 * quad + 4);
        const float4 c2 = *(const float4*)(rowC + 16 * quad + 8);
        const float4 c3 = *(const float4*)(rowC + 16 * quad + 12);

        // ---- hop0 logit: prefetched v0 regs . Ch ----
        float lg = dot4(va0, c0) + dot4(va1, c1) + dot4(va2, c2) + dot4(va3, c3);
        lg += __shfl_xor(lg, 16);
        lg += __shfl_xor(lg, 32);

        if (quad == 0 && mvalid) {
            kge += 1.f / (1.f + expf(-hrt));
            if (hop0) wsL[p] = lg;
        }

        // ---- hop1 Rh store: bf16, 2 x 16B ----
        if (mvalid && !hop0) {
            unsigned short* __restrict__ dst =
                wsRh + (size_t)(p - PAIR_PER_HOP) * DIM + 16 * quad;
            *(short8*)dst = pack8(c0, c1);
            *(short8*)(dst + 8) = pack8(c2, c3);
        }

        cnt += min(16, n - base);
        p = p2; hidx = h2; tidx = t2; iidx = i2;
    }

    const float l2tot = wave_reduce_sum(l2ht) + (float)cnt * Rsum;
    const float kgetot = wave_reduce_sum(kge);
    if (lane == 0) {
        const int bid = (r * JBLK + j) * WPB + w;
        ws_kge[bid] = kgetot;
        ws_l2[bid] = l2tot;
    }
}

// ---------------------------------------------------------------------------
// K2: attention — ONE WAVE PER BATCH ELEMENT, zero barriers (R12 rewrite).
// Grid: 256 blocks x 256 threads; wave w of block handles b = blk*4+w.
// All global gathers issue upfront; softmax is lane-butterfly + shfl
// broadcast; per-wave LDS sV only (same-wave DS ops are in-order).
// ---------------------------------------------------------------------------
__global__ __launch_bounds__(256) void ripple_attn(
    const int* __restrict__ items,
    const float* __restrict__ labels,
    const int* __restrict__ mt,
    const float* __restrict__ item_table,
    const float* __restrict__ W,
    const float* __restrict__ wsL,
    const unsigned short* __restrict__ wsRh,
    float* __restrict__ out,
    float* __restrict__ ws_bce)
{
    __shared__ __align__(16) float sV[4][DIM];   // per-wave u / v vector

    const int tid = (int)threadIdx.x;
    const int lane = tid & 63;
    const int w = tid >> 6;
    const int b = (int)blockIdx.x * 4 + w;

    // ================= all global loads issued upfront =================
    const float v0 = item_table[(size_t)items[b] * DIM + lane];

    const float lab = labels[b];

    float l0 = (lane < N_MEM) ? wsL[b * N_MEM + lane] : -1e30f;

    // one mt index per lane: hop = lane>>5, m = lane&31
    const int myidx = mt[(lane >> 5) * PAIR_PER_HOP + b * N_MEM + (lane & 31)];

    // 64 t-row gathers (indices broadcast by shuffle; loads pipeline)
    float treg[64];
    #pragma unroll
    for (int m = 0; m < 64; ++m) {
        const int idx = __shfl(myidx, m);
        treg[m] = item_table[(size_t)idx * DIM + lane];
    }

    // hop1 Rh fragment: lane pair (2*m1, 2*m1+1) covers slot m1's 64 dims
    const int m1 = lane >> 1;
    const int d1 = (lane & 1) * 32;
    short8 rv[4];
    #pragma unroll
    for (int e = 0; e < 4; ++e)
        rv[e] = *(const short8*)(wsRh + (size_t)(b * N_MEM + m1) * DIM + d1 + 8 * e);

    const float4* __restrict__ Wrow = (const float4*)(W + (size_t)lane * DIM);

    // ================= hop 0 softmax (lanes 0..31 hold logits) =============
    float mx = l0;
    #pragma unroll
    for (int d = 16; d >= 1; d >>= 1) mx = fmaxf(mx, __shfl_xor(mx, d));
    const float e0 = expf(l0 - mx);
    float se = (lane < N_MEM) ? e0 : 0.f;
    #pragma unroll
    for (int d = 16; d >= 1; d >>= 1) se += __shfl_xor(se, d);
    const float pe0 = e0 / se;                  // valid in lanes 0..31

    float o0 = 0.f;
    #pragma unroll
    for (int m = 0; m < N_MEM; ++m)
        o0 = fmaf(treg[m], __shfl(pe0, m), o0);

    // ================= v1 = W (v0 + o0) =================
    sV[w][lane] = v0 + o0;                       // same-wave DS: in-order
    float v1;
    {
        float a0 = 0.f, a1 = 0.f, a2 = 0.f, a3 = 0.f;
        #pragma unroll
        for (int k = 0; k < 16; ++k) {
            const float4 w4 = Wrow[k];
            const float4 u4 = *(const float4*)&sV[w][k * 4];
            a0 = fmaf(w4.x, u4.x, a0);
            a1 = fmaf(w4.y, u4.y, a1);
            a2 = fmaf(w4.z, u4.z, a2);
            a3 = fmaf(w4.w, u4.w, a3);
        }
        v1 = (a0 + a1) + (a2 + a3);
    }

    // ================= hop 1 logits: a[m] = <Rh[m], v1> =================
    sV[w][lane] = v1;
    float dp = 0.f;
    #pragma unroll
    for (int e = 0; e < 4; ++e) {
        const float4 va = *(const float4*)&sV[w][d1 + 8 * e];
        const float4 vb = *(const float4*)&sV[w][d1 + 8 * e + 4];
        dp += b2f(rv[e][0]) * va.x + b2f(rv[e][1]) * va.y
            + b2f(rv[e][2]) * va.z + b2f(rv[e][3]) * va.w
            + b2f(rv[e][4]) * vb.x + b2f(rv[e][5]) * vb.y
            + b2f(rv[e][6]) * vb.z + b2f(rv[e][7]) * vb.w;
    }
    dp += __shfl_xor(dp, 1);                     // pair-sum: full 64-dim dot
    const float a1v = __shfl(dp, (lane & 31) * 2);  // lane m gets a[m]

    // ================= hop 1 softmax =================
    float av = (lane < N_MEM) ? a1v : -1e30f;
    mx = av;
    #pragma unroll
    for (int d = 16; d >= 1; d >>= 1) mx = fmaxf(mx, __shfl_xor(mx, d));
    const float e1 = expf(av - mx);
    se = (lane < N_MEM) ? e1 : 0.f;
    #pragma unroll
    for (int d = 16; d >= 1; d >>= 1) se += __shfl_xor(se, d);
    const float pe1 = e1 / se;                  // valid in lanes 0..31

    float o1 = 0.f;
    #pragma unroll
    for (int m = 0; m < N_MEM; ++m)
        o1 = fmaf(treg[N_MEM + m], __shfl(pe1, m), o1);

    // ================= epilogue: v2 = W (v1 + o1); score =================
    const float y = o0 + o1;
    sV[w][lane] = v1 + o1;
    float v2;
    {
        float a0 = 0.f, a1_ = 0.f, a2 = 0.f, a3 = 0.f;
        #pragma unroll
        for (int k = 0; k < 16; ++k) {
            const float4 w4 = Wrow[k];
            const float4 u4 = *(const float4*)&sV[w][k * 4];
            a0 = fmaf(w4.x, u4.x, a0);
            a1_ = fmaf(w4.y, u4.y, a1_);
            a2 = fmaf(w4.z, u4.z, a2);
            a3 = fmaf(w4.w, u4.w, a3);
        }
        v2 = (a0 + a1_) + (a2 + a3);
    }

    float s = wave_reduce_sum(v2 * y);
    s = 1.f / (1.f + expf(-s));
    if (lane == 0) {
        out[b] = s;
        const float logp = fmaxf(logf(s), -100.f);
        const float lognp = fmaxf(logf(1.f - s), -100.f);
        ws_bce[b] = lab * logp + (1.f - lab) * lognp;
    }
}

// ---------------------------------------------------------------------------
// K3: loss finalize.
// ---------------------------------------------------------------------------
__global__ __launch_bounds__(256) void ripple_finalize(
    const float* __restrict__ ws_bce,
    const float* __restrict__ ws_kge,
    const float* __restrict__ ws_l2,
    float* __restrict__ out)
{
    __shared__ float sb[4], sk[4], sl[4];
    const int tid = (int)threadIdx.x;
    float bsum = 0.f, ksum = 0.f, lsum = 0.f;
    for (int i = tid; i < BATCH; i += 256) bsum += ws_bce[i];
    for (int i = tid; i < NBLK_PAIRS; i += 256) {
        ksum += ws_kge[i];
        lsum += ws_l2[i];
    }
    bsum = wave_reduce_sum(bsum);
    ksum = wave_reduce_sum(ksum);
    lsum = wave_reduce_sum(lsum);
    const int w = tid >> 6;
    if ((tid & 63) == 0) { sb[w] = bsum; sk[w] = ksum; sl[w] = lsum; }
    __syncthreads();
    if (tid == 0) {
        const float bs = sb[0] + sb[1] + sb[2] + sb[3];
        const float ks = sk[0] + sk[1] + sk[2] + sk[3];
        const float ls = sl[0] + sl[1] + sl[2] + sl[3];
        const float base_loss = -bs / (float)BATCH;
        const float kge_loss = -0.01f * (ks / (float)(BATCH * N_MEM));
        const float l2_loss = 1e-7f * ls;
        out[BATCH + 0] = base_loss + kge_loss + l2_loss;
        out[BATCH + 1] = base_loss;
        out[BATCH + 2] = kge_loss;
        out[BATCH + 3] = l2_loss;
    }
}

extern "C" void kernel_launch(void* const* d_in, const int* in_sizes, int n_in,
                              void* d_out, int out_size, void* d_ws, size_t ws_size,
                              hipStream_t stream) {
    const int* items        = (const int*)d_in[0];
    const float* labels     = (const float*)d_in[1];
    const int* mh           = (const int*)d_in[2];
    const int* mr           = (const int*)d_in[3];
    const int* mt           = (const int*)d_in[4];
    const float* item_table = (const float*)d_in[5];
    const float* rel_table  = (const float*)d_in[6];
    const float* W          = (const float*)d_in[7];
    float* out = (float*)d_out;

    // workspace: wsL[32768] f32 | wsRh[32768*64] bf16 (4.2MB) |
    //            list[N_REL*CAP] int | g_cnt[N_REL] |
    //            ws_bce[BATCH] | ws_kge[NBLK_PAIRS] | ws_l2[NBLK_PAIRS]
    float* ws = (float*)d_ws;
    float* wsL            = ws;
    unsigned short* wsRh  = (unsigned short*)(wsL + PAIR_PER_HOP);
    int*   list           = (int*)(wsRh + (size_t)PAIR_PER_HOP * DIM);
    int*   g_cnt          = list + N_REL * CAP;
    float* ws_bce         = (float*)(g_cnt + N_REL);
    float* ws_kge         = ws_bce + BATCH;
    float* ws_l2          = ws_kge + NBLK_PAIRS;

    hipMemsetAsync(g_cnt, 0, N_REL * sizeof(int), stream);
    ripple_bin<<<N_PAIR / 1024, 256, 0, stream>>>(mr, g_cnt, list);
    dim3 gpairs(JBLK, N_REL);
    ripple_pairs<<<gpairs, 256, 0, stream>>>(items, mh, mt, item_table, rel_table,
                                             g_cnt, list, wsL, wsRh, ws_kge, ws_l2);
    ripple_attn<<<BATCH / 4, 256, 0, stream>>>(items, labels, mt, item_table, W,
                                               wsL, wsRh, out, ws_bce);
    ripple_finalize<<<1, 256, 0, stream>>>(ws_bce, ws_kge, ws_l2, out);
}